// Round 2
// baseline (669.494 us; speedup 1.0000x reference)
//
#include <hip/hip_runtime.h>
#include <math.h>

#define NB 16
#define LL 512
#define CIN 32
#define DM 128
#define DS 16
#define DI 256
#define DTR 8
#define NCOL 3072
#define KTOT 65536
#define ROWS 8192
#define KCHUNK 1024
#define KSPLIT 64
#define OUTSZ 49152

__device__ __forceinline__ float sigmoidf_(float x){ return 1.f/(1.f+expf(-x)); }

// h = x @ W_in + b_in   (ROWS x 128, K=32)
__global__ void k_in(const float* __restrict__ x, const float* __restrict__ W,
                     const float* __restrict__ bias, float* __restrict__ h) {
  int idx = blockIdx.x*256 + threadIdx.x;
  int r = idx >> 7, c = idx & 127;
  const float* xr = x + r*CIN;
  float acc = bias[c];
  #pragma unroll
  for (int k=0;k<CIN;k++) acc = fmaf(xr[k], W[k*DM+c], acc);
  h[idx] = acc;
}

// xz = h @ W_inproj -> u_pre (cols 0..255), z (cols 256..511). K=128.
__global__ void k_inproj(const float* __restrict__ h, const float* __restrict__ W,
                         float* __restrict__ u_pre, float* __restrict__ z) {
  int t = threadIdx.x;
  int c0 = (t & 127)*4;
  int r0 = blockIdx.x*8 + (t>>7)*4;
  float acc[4][4] = {};
  for (int k=0;k<DM;k++) {
    float4 w = *(const float4*)(W + k*512 + c0);
    #pragma unroll
    for (int i=0;i<4;i++) {
      float hv = h[(r0+i)*DM + k];
      acc[i][0]=fmaf(hv,w.x,acc[i][0]); acc[i][1]=fmaf(hv,w.y,acc[i][1]);
      acc[i][2]=fmaf(hv,w.z,acc[i][2]); acc[i][3]=fmaf(hv,w.w,acc[i][3]);
    }
  }
  #pragma unroll
  for (int i=0;i<4;i++) {
    float4 v = make_float4(acc[i][0],acc[i][1],acc[i][2],acc[i][3]);
    if (c0 < 256) *(float4*)(u_pre + (r0+i)*DI + c0) = v;
    else          *(float4*)(z     + (r0+i)*DI + (c0-256)) = v;
  }
}

// causal depthwise conv (k=4) + bias + silu
__global__ void k_conv(const float* __restrict__ u_pre, const float* __restrict__ cw,
                       const float* __restrict__ cb, float* __restrict__ u) {
  int idx = blockIdx.x*256 + threadIdx.x; // NB*LL*DI
  int d = idx & 255;
  int l = (idx >> 8) & 511;
  int b = idx >> 17;
  float s = cb[d];
  #pragma unroll
  for (int j=0;j<4;j++) {
    int li = l - 3 + j;
    if (li >= 0) s = fmaf(cw[d*4+j], u_pre[(((b<<9)+li)<<8) + d], s);
  }
  u[idx] = s * sigmoidf_(s);
}

// xdbc = u @ W_xproj  (ROWS x 40, K=256)
__global__ void k_xproj(const float* __restrict__ u, const float* __restrict__ W,
                        float* __restrict__ xdbc) {
  int idx = blockIdx.x*256 + threadIdx.x; // ROWS*40
  int r = idx / 40, c = idx - r*40;
  const float* ur = u + r*DI;
  float acc = 0.f;
  for (int k=0;k<DI;k++) acc = fmaf(ur[k], W[k*40+c], acc);
  xdbc[idx] = acc;
}

// dt = softplus(xdbc[:, :8] @ W_dt + b_dt)
__global__ void k_dt(const float* __restrict__ xdbc, const float* __restrict__ Wdt,
                     const float* __restrict__ bdt, float* __restrict__ dt) {
  int idx = blockIdx.x*256 + threadIdx.x; // ROWS*256
  int r = idx >> 8, d = idx & 255;
  const float* xr = xdbc + r*40;
  float acc = bdt[d];
  #pragma unroll
  for (int j=0;j<DTR;j++) acc = fmaf(xr[j], Wdt[j*DI+d], acc);
  dt[idx] = (acc > 20.f) ? acc : log1pf(expf(acc));
}

// chunked scan, pass 1: per (b,d,chunk) local scan from 0; store end state + sum(dt)
__global__ void k_scan1(const float* __restrict__ dt, const float* __restrict__ u,
                        const float* __restrict__ xdbc, const float* __restrict__ A_log,
                        float* __restrict__ Hc, float* __restrict__ Sdt) {
  int b = blockIdx.x >> 4, c = blockIdx.x & 15, d = threadIdx.x;
  float A[16]; float hs[16];
  #pragma unroll
  for (int n=0;n<16;n++) { A[n] = -expf(A_log[d*16+n]); hs[n]=0.f; }
  float sdt = 0.f;
  int l0 = c*32;
  for (int l=l0; l<l0+32; ++l) {
    int row = (b<<9) + l;
    float dtv = dt[(row<<8) + d];
    float uv  = u[(row<<8) + d];
    sdt += dtv;
    float du = dtv*uv;
    const float* Bp = xdbc + row*40 + DTR;
    #pragma unroll
    for (int n=0;n<16;n++) {
      float a = expf(dtv*A[n]);
      hs[n] = fmaf(a, hs[n], du*Bp[n]);
    }
  }
  int base = ((((b<<8)+d)<<4) + c)<<4;
  #pragma unroll
  for (int n=0;n<16;n++) Hc[base+n] = hs[n];
  Sdt[(((b<<8)+d)<<4) + c] = sdt;
}

// pass 2: sequentially combine 16 chunks per (b,d); store each chunk's start state
__global__ void k_scan2(const float* __restrict__ A_log, const float* __restrict__ Hc,
                        const float* __restrict__ Sdt, float* __restrict__ Hst) {
  int b = blockIdx.x, d = threadIdx.x;
  float A[16]; float hs[16];
  #pragma unroll
  for (int n=0;n<16;n++) { A[n] = -expf(A_log[d*16+n]); hs[n]=0.f; }
  for (int c=0;c<16;c++) {
    int base = ((((b<<8)+d)<<4) + c)<<4;
    #pragma unroll
    for (int n=0;n<16;n++) Hst[base+n] = hs[n];
    float sdt = Sdt[(((b<<8)+d)<<4) + c];
    #pragma unroll
    for (int n=0;n<16;n++) hs[n] = fmaf(expf(A[n]*sdt), hs[n], Hc[base+n]);
  }
}

// pass 3: replay each chunk from correct start state; fuse y = (scan + u*D)*silu(z)
__global__ void k_scan3(const float* __restrict__ dt, const float* __restrict__ u,
                        const float* __restrict__ z, const float* __restrict__ xdbc,
                        const float* __restrict__ A_log, const float* __restrict__ Dp,
                        const float* __restrict__ Hst, float* __restrict__ ym) {
  int b = blockIdx.x >> 4, c = blockIdx.x & 15, d = threadIdx.x;
  float A[16]; float hs[16];
  int base = ((((b<<8)+d)<<4) + c)<<4;
  #pragma unroll
  for (int n=0;n<16;n++) { A[n] = -expf(A_log[d*16+n]); hs[n] = Hst[base+n]; }
  float Dv = Dp[d];
  int l0 = c*32;
  for (int l=l0; l<l0+32; ++l) {
    int row = (b<<9) + l;
    float dtv = dt[(row<<8) + d];
    float uv  = u[(row<<8) + d];
    float zv  = z[(row<<8) + d];
    float du = dtv*uv;
    const float* Bp = xdbc + row*40 + DTR;
    const float* Cp = xdbc + row*40 + DTR + DS;
    float y = 0.f;
    #pragma unroll
    for (int n=0;n<16;n++) {
      float a = expf(dtv*A[n]);
      hs[n] = fmaf(a, hs[n], du*Bp[n]);
      y = fmaf(hs[n], Cp[n], y);
    }
    y = fmaf(uv, Dv, y);
    ym[(row<<8)+d] = y * (zv * sigmoidf_(zv));
  }
}

// m_out = ym @ W_out (ROWS x 128, K=256)
__global__ void k_out(const float* __restrict__ ym, const float* __restrict__ W,
                      float* __restrict__ mo) {
  int t = threadIdx.x;
  int c0 = (t & 31)*4;
  int r0 = blockIdx.x*32 + (t>>5)*4;
  float acc[4][4] = {};
  for (int k=0;k<DI;k++) {
    float4 w = *(const float4*)(W + k*DM + c0);
    #pragma unroll
    for (int i=0;i<4;i++) {
      float v = ym[(r0+i)*DI + k];
      acc[i][0]=fmaf(v,w.x,acc[i][0]); acc[i][1]=fmaf(v,w.y,acc[i][1]);
      acc[i][2]=fmaf(v,w.z,acc[i][2]); acc[i][3]=fmaf(v,w.w,acc[i][3]);
    }
  }
  #pragma unroll
  for (int i=0;i<4;i++)
    *(float4*)(mo + (r0+i)*DM + c0) = make_float4(acc[i][0],acc[i][1],acc[i][2],acc[i][3]);
}

// final: pred partials = flat(16 x 65536) @ W_outproj(65536 x 3072), split-K
__global__ void k_final(const float* __restrict__ flat, const float* __restrict__ W,
                        float* __restrict__ part) {
  __shared__ float lds[16][KCHUNK];
  int t = threadIdx.x;
  int n0 = blockIdx.x * 128;
  int k0 = blockIdx.y * KCHUNK;
  for (int i=t; i<16*KCHUNK; i+=256) {
    int bb = i >> 10, kk = i & (KCHUNK-1);
    lds[bb][kk] = flat[bb*KTOT + k0 + kk];
  }
  __syncthreads();
  int c0 = n0 + (t & 31)*4;
  int b0 = (t >> 5)*2;
  float a00=0,a01=0,a02=0,a03=0,a10=0,a11=0,a12=0,a13=0;
  for (int kk=0; kk<KCHUNK; ++kk) {
    float4 w = *(const float4*)(W + (size_t)(k0+kk)*NCOL + c0);
    float f0 = lds[b0][kk], f1 = lds[b0+1][kk];
    a00=fmaf(f0,w.x,a00); a01=fmaf(f0,w.y,a01); a02=fmaf(f0,w.z,a02); a03=fmaf(f0,w.w,a03);
    a10=fmaf(f1,w.x,a10); a11=fmaf(f1,w.y,a11); a12=fmaf(f1,w.z,a12); a13=fmaf(f1,w.w,a13);
  }
  float* p = part + (size_t)blockIdx.y*OUTSZ;
  *(float4*)(p + b0*NCOL + c0)     = make_float4(a00,a01,a02,a03);
  *(float4*)(p + (b0+1)*NCOL + c0) = make_float4(a10,a11,a12,a13);
}

// out = sum_s part[s] + bias
__global__ void k_reduce(const float* __restrict__ part, const float* __restrict__ bias,
                         float* __restrict__ out) {
  int idx = blockIdx.x*256 + threadIdx.x; // OUTSZ
  float acc = bias[idx % NCOL];
  for (int s=0;s<KSPLIT;s++) acc += part[(size_t)s*OUTSZ + idx];
  out[idx] = acc;
}

extern "C" void kernel_launch(void* const* d_in, const int* in_sizes, int n_in,
                              void* d_out, int out_size, void* d_ws, size_t ws_size,
                              hipStream_t stream) {
  const float* x        = (const float*)d_in[0];
  const float* W_in     = (const float*)d_in[1];
  const float* b_in     = (const float*)d_in[2];
  const float* W_inproj = (const float*)d_in[3];
  const float* conv_w   = (const float*)d_in[4];
  const float* conv_b   = (const float*)d_in[5];
  const float* W_xproj  = (const float*)d_in[6];
  const float* W_dt     = (const float*)d_in[7];
  const float* b_dt     = (const float*)d_in[8];
  const float* A_log    = (const float*)d_in[9];
  const float* Dp       = (const float*)d_in[10];
  const float* W_out    = (const float*)d_in[11];
  const float* W_outproj= (const float*)d_in[12];
  const float* b_outproj= (const float*)d_in[13];
  float* out = (float*)d_out;
  float* ws  = (float*)d_ws;

  float* h     = ws;            // 1048576
  float* u_pre = ws + 1048576;  // 2097152
  float* z     = ws + 3145728;  // 2097152
  float* u     = ws + 5242880;  // 2097152
  float* xdbc  = ws + 7340032;  // 327680
  float* dt    = ws + 7667712;  // 2097152
  float* Hc    = ws + 9764864;  // 1048576
  float* Sdt   = ws + 10813440; // 65536
  float* Hst   = ws + 10878976; // 1048576
  float* ym    = ws + 11927552; // 2097152
  float* mo    = ws + 14024704; // 1048576
  float* part  = ws + 15073280; // 3145728   (total 18219008 floats = 72.9 MB)

  k_in    <<<4096, 256, 0, stream>>>(x, W_in, b_in, h);
  k_inproj<<<1024, 256, 0, stream>>>(h, W_inproj, u_pre, z);
  k_conv  <<<8192, 256, 0, stream>>>(u_pre, conv_w, conv_b, u);
  k_xproj <<<1280, 256, 0, stream>>>(u, W_xproj, xdbc);
  k_dt    <<<8192, 256, 0, stream>>>(xdbc, W_dt, b_dt, dt);
  k_scan1 <<<256,  256, 0, stream>>>(dt, u, xdbc, A_log, Hc, Sdt);
  k_scan2 <<<16,   256, 0, stream>>>(A_log, Hc, Sdt, Hst);
  k_scan3 <<<256,  256, 0, stream>>>(dt, u, z, xdbc, A_log, Dp, Hst, ym);
  k_out   <<<256,  256, 0, stream>>>(ym, W_out, mo);
  k_final <<<dim3(24, KSPLIT), 256, 0, stream>>>(mo, W_outproj, part);
  k_reduce<<<192,  256, 0, stream>>>(part, b_outproj, out);
}

// Round 3
// 367.758 us; speedup vs baseline: 1.8205x; 1.8205x over previous
//
#include <hip/hip_runtime.h>
#include <math.h>

#define NB 16
#define LL 512
#define CIN 32
#define DM 128
#define DS 16
#define DI 256
#define DTR 8
#define NCOL 3072
#define KTOT 65536
#define ROWS 8192
#define KC2 256
#define KS2 256
#define OUTSZ 49152

__device__ __forceinline__ float sigmoidf_(float x){ return 1.f/(1.f+expf(-x)); }

// h = x @ W_in + b_in   (ROWS x 128, K=32)
__global__ void k_in(const float* __restrict__ x, const float* __restrict__ W,
                     const float* __restrict__ bias, float* __restrict__ h) {
  int idx = blockIdx.x*256 + threadIdx.x;
  int r = idx >> 7, c = idx & 127;
  const float* xr = x + r*CIN;
  float acc = bias[c];
  #pragma unroll
  for (int k=0;k<CIN;k++) acc = fmaf(xr[k], W[k*DM+c], acc);
  h[idx] = acc;
}

// xz = h @ W_inproj -> u_pre (cols 0..255), z (cols 256..511). K=128.
__global__ void k_inproj(const float* __restrict__ h, const float* __restrict__ W,
                         float* __restrict__ u_pre, float* __restrict__ z) {
  int t = threadIdx.x;
  int c0 = (t & 127)*4;
  int r0 = blockIdx.x*8 + (t>>7)*4;
  float acc[4][4] = {};
  for (int k=0;k<DM;k++) {
    float4 w = *(const float4*)(W + k*512 + c0);
    #pragma unroll
    for (int i=0;i<4;i++) {
      float hv = h[(r0+i)*DM + k];
      acc[i][0]=fmaf(hv,w.x,acc[i][0]); acc[i][1]=fmaf(hv,w.y,acc[i][1]);
      acc[i][2]=fmaf(hv,w.z,acc[i][2]); acc[i][3]=fmaf(hv,w.w,acc[i][3]);
    }
  }
  #pragma unroll
  for (int i=0;i<4;i++) {
    float4 v = make_float4(acc[i][0],acc[i][1],acc[i][2],acc[i][3]);
    if (c0 < 256) *(float4*)(u_pre + (r0+i)*DI + c0) = v;
    else          *(float4*)(z     + (r0+i)*DI + (c0-256)) = v;
  }
}

// causal depthwise conv (k=4) + bias + silu
__global__ void k_conv(const float* __restrict__ u_pre, const float* __restrict__ cw,
                       const float* __restrict__ cb, float* __restrict__ u) {
  int idx = blockIdx.x*256 + threadIdx.x; // NB*LL*DI
  int d = idx & 255;
  int l = (idx >> 8) & 511;
  int b = idx >> 17;
  float s = cb[d];
  #pragma unroll
  for (int j=0;j<4;j++) {
    int li = l - 3 + j;
    if (li >= 0) s = fmaf(cw[d*4+j], u_pre[(((b<<9)+li)<<8) + d], s);
  }
  u[idx] = s * sigmoidf_(s);
}

// xdbc = u @ W_xproj  (ROWS x 40, K=256)
__global__ void k_xproj(const float* __restrict__ u, const float* __restrict__ W,
                        float* __restrict__ xdbc) {
  int idx = blockIdx.x*256 + threadIdx.x; // ROWS*40
  int r = idx / 40, c = idx - r*40;
  const float* ur = u + r*DI;
  float acc = 0.f;
  for (int k=0;k<DI;k++) acc = fmaf(ur[k], W[k*40+c], acc);
  xdbc[idx] = acc;
}

// dt = softplus(xdbc[:, :8] @ W_dt + b_dt)
__global__ void k_dt(const float* __restrict__ xdbc, const float* __restrict__ Wdt,
                     const float* __restrict__ bdt, float* __restrict__ dt) {
  int idx = blockIdx.x*256 + threadIdx.x; // ROWS*256
  int r = idx >> 8, d = idx & 255;
  const float* xr = xdbc + r*40;
  float acc = bdt[d];
  #pragma unroll
  for (int j=0;j<DTR;j++) acc = fmaf(xr[j], Wdt[j*DI+d], acc);
  dt[idx] = (acc > 20.f) ? acc : log1pf(expf(acc));
}

// chunked scan, pass 1: per (b,d,chunk) local scan from 0; store end state + sum(dt)
__global__ void k_scan1(const float* __restrict__ dt, const float* __restrict__ u,
                        const float* __restrict__ xdbc, const float* __restrict__ A_log,
                        float* __restrict__ Hc, float* __restrict__ Sdt) {
  int b = blockIdx.x >> 4, c = blockIdx.x & 15, d = threadIdx.x;
  float A[16]; float hs[16];
  #pragma unroll
  for (int n=0;n<16;n++) { A[n] = -expf(A_log[d*16+n]); hs[n]=0.f; }
  float sdt = 0.f;
  int l0 = c*32;
  for (int l=l0; l<l0+32; ++l) {
    int row = (b<<9) + l;
    float dtv = dt[(row<<8) + d];
    float uv  = u[(row<<8) + d];
    sdt += dtv;
    float du = dtv*uv;
    const float* Bp = xdbc + row*40 + DTR;
    #pragma unroll
    for (int n=0;n<16;n++) {
      float a = expf(dtv*A[n]);
      hs[n] = fmaf(a, hs[n], du*Bp[n]);
    }
  }
  int base = ((((b<<8)+d)<<4) + c)<<4;
  #pragma unroll
  for (int n=0;n<16;n++) Hc[base+n] = hs[n];
  Sdt[(((b<<8)+d)<<4) + c] = sdt;
}

// pass 2: one thread per (b,d,n) chain; combine 16 chunks; store chunk start states
__global__ void k_scan2(const float* __restrict__ A_log, const float* __restrict__ Hc,
                        const float* __restrict__ Sdt, float* __restrict__ Hst) {
  int idx = blockIdx.x*256 + threadIdx.x;   // NB*DI*DS = 65536
  int n  = idx & 15;
  int bd = idx >> 4;                        // b*256 + d
  int d  = bd & 255;
  float A = -expf(A_log[d*16+n]);
  float hs = 0.f;
  int base = bd << 8;                       // bd*256
  #pragma unroll
  for (int c=0;c<16;c++) {
    Hst[base + c*16 + n] = hs;
    float sdt = Sdt[(bd<<4)+c];
    hs = fmaf(expf(A*sdt), hs, Hc[base + c*16 + n]);
  }
}

// pass 3: replay each chunk from correct start state; fuse y = (scan + u*D)*silu(z)
__global__ void k_scan3(const float* __restrict__ dt, const float* __restrict__ u,
                        const float* __restrict__ z, const float* __restrict__ xdbc,
                        const float* __restrict__ A_log, const float* __restrict__ Dp,
                        const float* __restrict__ Hst, float* __restrict__ ym) {
  int b = blockIdx.x >> 4, c = blockIdx.x & 15, d = threadIdx.x;
  float A[16]; float hs[16];
  int base = ((((b<<8)+d)<<4) + c)<<4;
  #pragma unroll
  for (int n=0;n<16;n++) { A[n] = -expf(A_log[d*16+n]); hs[n] = Hst[base+n]; }
  float Dv = Dp[d];
  int l0 = c*32;
  for (int l=l0; l<l0+32; ++l) {
    int row = (b<<9) + l;
    float dtv = dt[(row<<8) + d];
    float uv  = u[(row<<8) + d];
    float zv  = z[(row<<8) + d];
    float du = dtv*uv;
    const float* Bp = xdbc + row*40 + DTR;
    const float* Cp = xdbc + row*40 + DTR + DS;
    float y = 0.f;
    #pragma unroll
    for (int n=0;n<16;n++) {
      float a = expf(dtv*A[n]);
      hs[n] = fmaf(a, hs[n], du*Bp[n]);
      y = fmaf(hs[n], Cp[n], y);
    }
    y = fmaf(uv, Dv, y);
    ym[(row<<8)+d] = y * (zv * sigmoidf_(zv));
  }
}

// m_out = ym @ W_out (ROWS x 128, K=256)
__global__ void k_out(const float* __restrict__ ym, const float* __restrict__ W,
                      float* __restrict__ mo) {
  int t = threadIdx.x;
  int c0 = (t & 31)*4;
  int r0 = blockIdx.x*32 + (t>>5)*4;
  float acc[4][4] = {};
  for (int k=0;k<DI;k++) {
    float4 w = *(const float4*)(W + k*DM + c0);
    #pragma unroll
    for (int i=0;i<4;i++) {
      float v = ym[(r0+i)*DI + k];
      acc[i][0]=fmaf(v,w.x,acc[i][0]); acc[i][1]=fmaf(v,w.y,acc[i][1]);
      acc[i][2]=fmaf(v,w.z,acc[i][2]); acc[i][3]=fmaf(v,w.w,acc[i][3]);
    }
  }
  #pragma unroll
  for (int i=0;i<4;i++)
    *(float4*)(mo + (r0+i)*DM + c0) = make_float4(acc[i][0],acc[i][1],acc[i][2],acc[i][3]);
}

// final: pred partials = flat(16 x 65536) @ W_outproj(65536 x 3072), split-K.
// Each thread: 4 cols x all 16 rows (64 acc VGPRs). Wave reads 1KB contiguous W.
__global__ void __launch_bounds__(256) k_final(
    const float* __restrict__ flat, const float* __restrict__ W,
    float* __restrict__ part) {
  __shared__ float lds[KC2][16];           // transposed: [kk][b], 16 KB
  int t = threadIdx.x;
  int n0 = blockIdx.x * 1024;              // 3 n-tiles of 1024 cols
  int k0 = blockIdx.y * KC2;               // 256 k-splits of 256
  // stage flat chunk (16 rows x 256 k) transposed into LDS
  for (int i = t; i < 16*(KC2/4); i += 256) {
    int bb  = i >> 6;                      // 0..15
    int kk4 = i & 63;                      // 0..63
    float4 v = *(const float4*)(flat + bb*KTOT + k0 + kk4*4);
    lds[kk4*4+0][bb] = v.x; lds[kk4*4+1][bb] = v.y;
    lds[kk4*4+2][bb] = v.z; lds[kk4*4+3][bb] = v.w;
  }
  __syncthreads();
  int c0 = n0 + t*4;
  float4 acc[16];
  #pragma unroll
  for (int b=0;b<16;b++) acc[b] = make_float4(0.f,0.f,0.f,0.f);
  const float* Wp = W + (size_t)k0*NCOL + c0;
  for (int kk=0; kk<KC2; kk+=2) {
    float4 w0 = *(const float4*)(Wp + (size_t)kk*NCOL);
    float4 w1 = *(const float4*)(Wp + (size_t)(kk+1)*NCOL);
    const float4* f0 = (const float4*)&lds[kk][0];
    const float4* f1 = (const float4*)&lds[kk+1][0];
    #pragma unroll
    for (int q=0;q<4;q++) {
      float4 fa = f0[q], fb = f1[q];
      float fs[8] = {fa.x,fa.y,fa.z,fa.w, fb.x,fb.y,fb.z,fb.w};
      #pragma unroll
      for (int j=0;j<4;j++) {
        int b = q*4+j;
        acc[b].x=fmaf(fs[j],w0.x,acc[b].x); acc[b].y=fmaf(fs[j],w0.y,acc[b].y);
        acc[b].z=fmaf(fs[j],w0.z,acc[b].z); acc[b].w=fmaf(fs[j],w0.w,acc[b].w);
        acc[b].x=fmaf(fs[4+j],w1.x,acc[b].x); acc[b].y=fmaf(fs[4+j],w1.y,acc[b].y);
        acc[b].z=fmaf(fs[4+j],w1.z,acc[b].z); acc[b].w=fmaf(fs[4+j],w1.w,acc[b].w);
      }
    }
  }
  float* p = part + (size_t)blockIdx.y*OUTSZ;
  #pragma unroll
  for (int b=0;b<16;b++) *(float4*)(p + b*NCOL + c0) = acc[b];
}

// out = sum_s part[s] + bias
__global__ void k_reduce(const float* __restrict__ part, const float* __restrict__ bias,
                         float* __restrict__ out) {
  int idx = blockIdx.x*256 + threadIdx.x; // OUTSZ
  float acc = bias[idx % NCOL];
  for (int s=0;s<KS2;s++) acc += part[(size_t)s*OUTSZ + idx];
  out[idx] = acc;
}

extern "C" void kernel_launch(void* const* d_in, const int* in_sizes, int n_in,
                              void* d_out, int out_size, void* d_ws, size_t ws_size,
                              hipStream_t stream) {
  const float* x        = (const float*)d_in[0];
  const float* W_in     = (const float*)d_in[1];
  const float* b_in     = (const float*)d_in[2];
  const float* W_inproj = (const float*)d_in[3];
  const float* conv_w   = (const float*)d_in[4];
  const float* conv_b   = (const float*)d_in[5];
  const float* W_xproj  = (const float*)d_in[6];
  const float* W_dt     = (const float*)d_in[7];
  const float* b_dt     = (const float*)d_in[8];
  const float* A_log    = (const float*)d_in[9];
  const float* Dp       = (const float*)d_in[10];
  const float* W_out    = (const float*)d_in[11];
  const float* W_outproj= (const float*)d_in[12];
  const float* b_outproj= (const float*)d_in[13];
  float* out = (float*)d_out;
  float* ws  = (float*)d_ws;

  float* h     = ws;            // 1048576
  float* u_pre = ws + 1048576;  // 2097152
  float* z     = ws + 3145728;  // 2097152
  float* u     = ws + 5242880;  // 2097152
  float* xdbc  = ws + 7340032;  // 327680
  float* dt    = ws + 7667712;  // 2097152
  float* Hc    = ws + 9764864;  // 1048576
  float* Sdt   = ws + 10813440; // 65536
  float* Hst   = ws + 10878976; // 1048576
  float* ym    = ws + 11927552; // 2097152
  float* mo    = ws + 14024704; // 1048576
  float* part  = ws + 15073280; // 12582912 (KS2*OUTSZ) -> total ~110.6 MB

  k_in    <<<4096, 256, 0, stream>>>(x, W_in, b_in, h);
  k_inproj<<<1024, 256, 0, stream>>>(h, W_inproj, u_pre, z);
  k_conv  <<<8192, 256, 0, stream>>>(u_pre, conv_w, conv_b, u);
  k_xproj <<<1280, 256, 0, stream>>>(u, W_xproj, xdbc);
  k_dt    <<<8192, 256, 0, stream>>>(xdbc, W_dt, b_dt, dt);
  k_scan1 <<<256,  256, 0, stream>>>(dt, u, xdbc, A_log, Hc, Sdt);
  k_scan2 <<<256,  256, 0, stream>>>(A_log, Hc, Sdt, Hst);
  k_scan3 <<<256,  256, 0, stream>>>(dt, u, z, xdbc, A_log, Dp, Hst, ym);
  k_out   <<<256,  256, 0, stream>>>(ym, W_out, mo);
  k_final <<<dim3(3, KS2), 256, 0, stream>>>(mo, W_outproj, part);
  k_reduce<<<192,  256, 0, stream>>>(part, b_outproj, out);
}